// Round 10
// baseline (433.803 us; speedup 1.0000x reference)
//
#include <hip/hip_runtime.h>

#define NN 8192
#define FF 256
#define PST 136   // P LDS row stride in halves (128 + 8 pad, 16B-aligned)

typedef _Float16 h8 __attribute__((ext_vector_type(8)));
typedef _Float16 h4 __attribute__((ext_vector_type(4)));
typedef float    f4 __attribute__((ext_vector_type(4)));
typedef int      i4v __attribute__((ext_vector_type(4)));

// monotone float<->uint encoding for atomicMax on fp32
__device__ __forceinline__ unsigned fenc(float x) {
  unsigned u = __float_as_uint(x);
  return (u & 0x80000000u) ? ~u : (u | 0x80000000u);
}
__device__ __forceinline__ float fdec(unsigned e) {
  unsigned u = (e & 0x80000000u) ? (e ^ 0x80000000u) : ~e;
  return __uint_as_float(u);
}

// lgkm-only barrier (CK block_sync_lds pattern): publishes LDS writes without
// draining vmem (plain __syncthreads emits s_waitcnt vmcnt(0) -> kills the
// adj prefetch pipeline).
__device__ __forceinline__ void sync_lds() {
  __builtin_amdgcn_s_waitcnt(0xc07f);   // lgkmcnt(0), vmcnt/expcnt ignored
  __builtin_amdgcn_s_barrier();
}

// ---------------- Kernel 1: Wh = h@W (fp32 vector), s1, s2(f16), wfrag -------
// grid 512 x 256 thr. Block = 16 rows of h = half of k-tile (blockIdx>>1).
// wfrag[(kt*16+n)*512 + lane*8 + j] = Wh[kt*32 + (lane>>4)*8 + j][n*16 + (lane&15)]
// R4 fix: s2max via per-block LDS reduction + ONE atomicMax per block
// (was 8192 single-address device atomics -> ~90 us serialization tail).
__global__ __launch_bounds__(256) void k_wh(
    const float* __restrict__ h, const float* __restrict__ W,
    const float* __restrict__ a, _Float16* __restrict__ wfrag,
    float* __restrict__ s1, _Float16* __restrict__ s2h,
    unsigned* __restrict__ s2maxe) {
  __shared__ float hs[16 * 256];        // 16 KB
  __shared__ _Float16 whs[16 * 264];    // 8.25 KB
  __shared__ unsigned bm[4];            // per-wave p2-max (fenc domain)
  const int t = threadIdx.x;
  const int r0 = blockIdx.x * 16;
#pragma unroll
  for (int i = 0; i < 4; ++i) {
    int idx = i * 1024 + t * 4;
    *(f4*)&hs[idx] = *(const f4*)&h[(size_t)r0 * 256 + idx];
  }
  __syncthreads();
  const int lane = t & 63;
  const int wv = t >> 6;        // 0..3
  const int rg = wv * 4;
  const int c4 = lane * 4;
  float acc[4][4];
#pragma unroll
  for (int i = 0; i < 4; ++i)
#pragma unroll
    for (int k = 0; k < 4; ++k) acc[i][k] = 0.f;
  f4 w[8];
#pragma unroll
  for (int i = 0; i < 8; ++i) w[i] = *(const f4*)&W[i * 256 + c4];
  for (int f = 0; f < 256; f += 8) {
    f4 nw[8];
    if (f < 248) {
#pragma unroll
      for (int i = 0; i < 8; ++i) nw[i] = *(const f4*)&W[(f + 8 + i) * 256 + c4];
    }
#pragma unroll
    for (int i = 0; i < 4; ++i) {
      f4 h0 = *(const f4*)&hs[(rg + i) * 256 + f];
      f4 h1 = *(const f4*)&hs[(rg + i) * 256 + f + 4];
#pragma unroll
      for (int k = 0; k < 4; ++k)
        acc[i][k] += h0[0]*w[0][k] + h0[1]*w[1][k] + h0[2]*w[2][k] + h0[3]*w[3][k]
                   + h1[0]*w[4][k] + h1[1]*w[5][k] + h1[2]*w[6][k] + h1[3]*w[7][k];
    }
    if (f < 248) {
#pragma unroll
      for (int i = 0; i < 8; ++i) w[i] = nw[i];
    }
  }
  float a1v[4], a2v[4];
#pragma unroll
  for (int k = 0; k < 4; ++k) { a1v[k] = a[c4 + k]; a2v[k] = a[256 + c4 + k]; }
  unsigned wmax = 0u;   // fenc domain: 0 < fenc(x) for all finite x
#pragma unroll
  for (int i = 0; i < 4; ++i) {
    h4 hh;
    float p1 = 0.f, p2 = 0.f;
#pragma unroll
    for (int k = 0; k < 4; ++k) {
      hh[k] = (_Float16)acc[i][k];
      p1 += acc[i][k] * a1v[k];
      p2 += acc[i][k] * a2v[k];
    }
    *(h4*)&whs[(rg + i) * 264 + c4] = hh;
#pragma unroll
    for (int off = 32; off; off >>= 1) {
      p1 += __shfl_xor(p1, off);
      p2 += __shfl_xor(p2, off);
    }
    if (lane == 0) {
      const int r = r0 + rg + i;
      s1[r] = p1;
      s2h[r] = (_Float16)p2;
      const unsigned e = fenc(p2);
      wmax = (e > wmax) ? e : wmax;
    }
  }
  if (lane == 0) bm[wv] = wmax;
  __syncthreads();
  if (t == 0) {
    unsigned m01 = (bm[0] > bm[1]) ? bm[0] : bm[1];
    unsigned m23 = (bm[2] > bm[3]) ? bm[2] : bm[3];
    atomicMax(s2maxe, (m01 > m23) ? m01 : m23);   // 1 atomic per block (512 total)
  }
  {
    const int kt = blockIdx.x >> 1;
    const int hb = blockIdx.x & 1;
    const int lp = hb * 32 + (t & 31);
    const int kb = ((t & 31) >> 4) * 8;
    const int m16e = t & 15;
#pragma unroll
    for (int p = 0; p < 2; ++p) {
      const int n = (t >> 5) + p * 8;
      h8 v;
#pragma unroll
      for (int j = 0; j < 8; ++j) v[j] = whs[(kb + j) * 264 + n * 16 + m16e];
      *(h8*)&wfrag[(((size_t)kt * 16 + n) << 9) + lp * 8] = v;
    }
  }
}

// ---------------- Kernel 2: fused attention ----------------------------------
// R10: R5 geometry (64-row, grid 512, LB(512,4), 16 periods, scores->bar->MFMA)
// but wave->output partition changed 1m x 8n -> 2m x 4n (each wave owns a
// 32x64 tile). Rationale: in 1x8 every wave ds_reads the ENTIRE 16 KB P panel
// (8x amplification = 256 KB/period/CU = ~2K cyc + ~1K cyc bank conflicts --
// the largest modeled serial term). 2x4 halves A-LDS traffic; the B 2x re-read
// within a block is L1-absorbed (both nt readers near-simultaneous). B frags
// staged in two batches of 8 (ks01 pre-barrier, ks23 inside MFMA region) to
// cap peak VGPR (~128 budget at LB(512,4); R6 proved the spill cliff).
// Scores / P layout / accumulation order unchanged -> absmax bit-identical.
__global__ __launch_bounds__(512, 4) void k_gat(
    const int* __restrict__ adj, const _Float16* __restrict__ wfrag,
    const float* __restrict__ s1g, const _Float16* __restrict__ s2h,
    const unsigned* __restrict__ s2maxe,
    float* __restrict__ o0, float* __restrict__ o1,
    float* __restrict__ o2, float* __restrict__ o3,
    float* __restrict__ lbuf) {
  __shared__ _Float16 P[2][64 * PST];   // 34 KB
  __shared__ _Float16 s2l[2048];        // 4 KB
  const int t = threadIdx.x;
  const int lane = t & 63;
  const int w = t >> 6;          // 0..7
  const int wm = w >> 2;         // 0..1: output rows [wm*32, wm*32+32)
  const int wn = w & 3;          // 0..3: output cols [wn*64, wn*64+64)
  const int q = lane >> 4;       // 0..3
  const int m16 = lane & 15;
  const int rt = (int)blockIdx.x >> 2;
  const int kq = (int)blockIdx.x & 3;
  const int r0 = rt * 64;

  if (t < 256) ((h8*)s2l)[t] = ((const h8*)(s2h + kq * 2048))[t];  // kq-quarter s2

  const int srA = 8 * w + q;                 // lane's two score rows (local)
  const int srB = srA + 4;
  const float s2m = fdec(*s2maxe);
  const float s1A = s1g[r0 + srA];
  const float s1B = s1g[r0 + srB];
  const float uA0 = s1A + s2m, uB0 = s1B + s2m;
  const float miA = fmaxf(uA0, 0.2f * uA0);  // >= leaky(s1+s2[j]) for all j
  const float miB = fmaxf(uB0, 0.2f * uB0);
  const float sAmi = s1A - miA, sBmi = s1B - miB;

  f4 acc[2][4];                  // [mt][nt], 16x16 tiles of the 32x64 wave tile
#pragma unroll
  for (int m = 0; m < 2; ++m)
#pragma unroll
    for (int n = 0; n < 4; ++n)
#pragma unroll
      for (int e = 0; e < 4; ++e) acc[m][n][e] = 0.f;
  float lsA = 0.f, lsB = 0.f;

  const int* adjA = adj + (size_t)(r0 + srA) * NN + kq * 2048 + m16 * 8;
  const int* adjB = adj + (size_t)(r0 + srB) * NN + kq * 2048 + m16 * 8;
  __syncthreads();   // s2l ready (once; full drain harmless here)

  // preload adj for period 0
  i4v a0 = *(const i4v*)(adjA);
  i4v a1 = *(const i4v*)(adjA + 4);
  i4v b0 = *(const i4v*)(adjB);
  i4v b1 = *(const i4v*)(adjB + 4);

  for (int p = 0; p < 16; ++p) {
    // base of this period's wfrag block; n-tile index = wn*4 + nt
    const _Float16* wfb =
        wfrag + ((((size_t)(kq * 64 + p * 4)) * 16 + wn * 4) << 9) + lane * 8;
    // (1) B-frags batch 0 (ks 0,1 x nt 0..3): oldest vmem of the period
    h8 bb0[8];
#pragma unroll
    for (int ks = 0; ks < 2; ++ks)
#pragma unroll
      for (int nt = 0; nt < 4; ++nt)
        bb0[ks * 4 + nt] = *(const h8*)(wfb + ks * 8192 + nt * 512);
    // (2) adj prefetch for p+1 (HBM; consumed next period)
    i4v na0 = a0, na1 = a1, nb0 = b0, nb1 = b1;
    if (p < 15) {
      na0 = *(const i4v*)(adjA + (p + 1) * 128);
      na1 = *(const i4v*)(adjA + (p + 1) * 128 + 4);
      nb0 = *(const i4v*)(adjB + (p + 1) * 128);
      nb1 = *(const i4v*)(adjB + (p + 1) * 128 + 4);
    }
    // (3) scores for both rows: p = exp(leaky(s1+s2) - mi)
    const h8 s2c = *(const h8*)&s2l[p * 128 + m16 * 8];
    h8 pA, pB;
#pragma unroll
    for (int j = 0; j < 8; ++j) {
      const float s2v = (float)s2c[j];
      const int mA = (j < 4) ? a0[j] : a1[j - 4];
      const int mB = (j < 4) ? b0[j] : b1[j - 4];
      const float uA = s1A + s2v;
      const float uB = s1B + s2v;
      const float argA = sAmi + s2v - 0.8f * fminf(uA, 0.f);
      const float argB = sBmi + s2v - 0.8f * fminf(uB, 0.f);
      const float pvA = (mA > 0) ? __expf(argA) : 0.f;
      const float pvB = (mB > 0) ? __expf(argB) : 0.f;
      lsA += pvA; pA[j] = (_Float16)pvA;
      lsB += pvB; pB[j] = (_Float16)pvB;
    }
    _Float16* Pb = &P[p & 1][0];
    *(h8*)&Pb[srA * PST + m16 * 8] = pA;
    *(h8*)&Pb[srB * PST + m16 * 8] = pB;
    // (4) publish P without draining vmem
    sync_lds();
    // (5) MFMA: A rows [wm*32, wm*32+32) only (2 ds_read per ks, was 4).
    const int ra0 = (wm * 32 + m16) * PST;
    const int ra1 = (wm * 32 + 16 + m16) * PST;
    // ks 0 (bb0[0..3])
    {
      const h8 A0 = *(const h8*)&Pb[ra0 + 0 * 32 + q * 8];
      const h8 A1 = *(const h8*)&Pb[ra1 + 0 * 32 + q * 8];
#pragma unroll
      for (int nt = 0; nt < 4; ++nt) {
        acc[0][nt] = __builtin_amdgcn_mfma_f32_16x16x32_f16(A0, bb0[nt], acc[0][nt], 0, 0, 0);
        acc[1][nt] = __builtin_amdgcn_mfma_f32_16x16x32_f16(A1, bb0[nt], acc[1][nt], 0, 0, 0);
      }
    }
    // B-frags batch 1 (ks 2,3): issued after bb0[0..3] last use -> peak live
    // B stays ~12 frags (VGPR cap), latency hidden under ks1 MFMAs + coresident waves
    h8 bb1[8];
#pragma unroll
    for (int ks = 0; ks < 2; ++ks)
#pragma unroll
      for (int nt = 0; nt < 4; ++nt)
        bb1[ks * 4 + nt] = *(const h8*)(wfb + (ks + 2) * 8192 + nt * 512);
    // ks 1 (bb0[4..7])
    {
      const h8 A0 = *(const h8*)&Pb[ra0 + 1 * 32 + q * 8];
      const h8 A1 = *(const h8*)&Pb[ra1 + 1 * 32 + q * 8];
#pragma unroll
      for (int nt = 0; nt < 4; ++nt) {
        acc[0][nt] = __builtin_amdgcn_mfma_f32_16x16x32_f16(A0, bb0[4 + nt], acc[0][nt], 0, 0, 0);
        acc[1][nt] = __builtin_amdgcn_mfma_f32_16x16x32_f16(A1, bb0[4 + nt], acc[1][nt], 0, 0, 0);
      }
    }
    // ks 2 (bb1[0..3])
    {
      const h8 A0 = *(const h8*)&Pb[ra0 + 2 * 32 + q * 8];
      const h8 A1 = *(const h8*)&Pb[ra1 + 2 * 32 + q * 8];
#pragma unroll
      for (int nt = 0; nt < 4; ++nt) {
        acc[0][nt] = __builtin_amdgcn_mfma_f32_16x16x32_f16(A0, bb1[nt], acc[0][nt], 0, 0, 0);
        acc[1][nt] = __builtin_amdgcn_mfma_f32_16x16x32_f16(A1, bb1[nt], acc[1][nt], 0, 0, 0);
      }
    }
    // ks 3 (bb1[4..7])
    {
      const h8 A0 = *(const h8*)&Pb[ra0 + 3 * 32 + q * 8];
      const h8 A1 = *(const h8*)&Pb[ra1 + 3 * 32 + q * 8];
#pragma unroll
      for (int nt = 0; nt < 4; ++nt) {
        acc[0][nt] = __builtin_amdgcn_mfma_f32_16x16x32_f16(A0, bb1[4 + nt], acc[0][nt], 0, 0, 0);
        acc[1][nt] = __builtin_amdgcn_mfma_f32_16x16x32_f16(A1, bb1[4 + nt], acc[1][nt], 0, 0, 0);
      }
    }
    a0 = na0; a1 = na1; b0 = nb0; b1 = nb1;
  }

  // partial softmax denominators: reduce over the 16 m16 lanes
  lsA += __shfl_xor(lsA, 1);
  lsA += __shfl_xor(lsA, 2);
  lsA += __shfl_xor(lsA, 4);
  lsA += __shfl_xor(lsA, 8);
  lsB += __shfl_xor(lsB, 1);
  lsB += __shfl_xor(lsB, 2);
  lsB += __shfl_xor(lsB, 4);
  lsB += __shfl_xor(lsB, 8);
  if (m16 == 0) {
    lbuf[kq * NN + r0 + srA] = lsA;
    lbuf[kq * NN + r0 + srB] = lsB;
  }

  // partial O: plain stores (each element written once per kq)
  float* ob = (kq == 0) ? o0 : (kq == 1) ? o1 : (kq == 2) ? o2 : o3;
#pragma unroll
  for (int mt = 0; mt < 2; ++mt)
#pragma unroll
    for (int nt = 0; nt < 4; ++nt)
#pragma unroll
      for (int v = 0; v < 4; ++v)
        ob[(size_t)(r0 + wm * 32 + mt * 16 + q * 4 + v) * FF + wn * 64 + nt * 16 + m16] =
            acc[mt][nt][v];
}

// ---------------- Kernel 3: combine quarters, normalize, elu -----------------
__global__ __launch_bounds__(256) void k_fin(
    float* __restrict__ out, const float* __restrict__ o1,
    const float* __restrict__ o2, const float* __restrict__ o3,
    const float* __restrict__ lbuf) {
  const int t = threadIdx.x;
  const int row = blockIdx.x * 16 + (t >> 4);
  const int c0 = (t & 15) * 16;
  const float linv = 1.0f / (lbuf[row] + lbuf[NN + row] +
                             lbuf[2 * NN + row] + lbuf[3 * NN + row]);
#pragma unroll
  for (int i = 0; i < 4; ++i) {
    f4 v0 = *(const f4*)&out[(size_t)row * FF + c0 + i * 4];
    f4 v1 = *(const f4*)&o1[(size_t)row * FF + c0 + i * 4];
    f4 v2 = *(const f4*)&o2[(size_t)row * FF + c0 + i * 4];
    f4 v3 = *(const f4*)&o3[(size_t)row * FF + c0 + i * 4];
    f4 o;
#pragma unroll
    for (int e = 0; e < 4; ++e) {
      float x = (v0[e] + v1[e] + v2[e] + v3[e]) * linv;
      o[e] = (x > 0.f) ? x : (__expf(x) - 1.f);
    }
    *(f4*)&out[(size_t)row * FF + c0 + i * 4] = o;
  }
}

extern "C" void kernel_launch(void* const* d_in, const int* in_sizes, int n_in,
                              void* d_out, int out_size, void* d_ws, size_t ws_size,
                              hipStream_t stream) {
  const float* h   = (const float*)d_in[0];
  const int*   adj = (const int*)d_in[1];
  const float* W   = (const float*)d_in[2];
  const float* a   = (const float*)d_in[3];
  float* out = (float*)d_out;

  char* ws = (char*)d_ws;
  _Float16* wfrag = (_Float16*)ws;                                 // 4 MB
  float*    o1    = (float*)(ws + (4u << 20));                     // 8 MB (kq=1)
  float*    o2    = (float*)(ws + (12u << 20));                    // 8 MB (kq=2)
  float*    o3    = (float*)(ws + (20u << 20));                    // 8 MB (kq=3)
  float*    lbuf  = (float*)(ws + (28u << 20));                    // 128 KB (4 x 8192)
  unsigned* s2me  = (unsigned*)(ws + (28u << 20) + 131072);        // 4 B (+60 pad)
  float*    s1    = (float*)(ws + (28u << 20) + 131072 + 64);      // 32 KB
  _Float16* s2h   = (_Float16*)(ws + (28u << 20) + 131072 + 64 + 32768); // 16 KB

  hipMemsetAsync(s2me, 0, 4, stream);   // fenc-domain -inf
  k_wh<<<512, 256, 0, stream>>>(h, W, a, wfrag, s1, s2h, s2me);
  k_gat<<<512, 512, 0, stream>>>(adj, wfrag, s1, s2h, s2me, out, o1, o2, o3, lbuf);
  k_fin<<<512, 256, 0, stream>>>(out, o1, o2, o3, lbuf);
}

// Round 11
// 416.345 us; speedup vs baseline: 1.0419x; 1.0419x over previous
//
#include <hip/hip_runtime.h>

#define NN 8192
#define FF 256
#define PST 136   // P LDS row stride in halves (128 + 8 pad, 16B-aligned)

typedef _Float16 h8 __attribute__((ext_vector_type(8)));
typedef _Float16 h4 __attribute__((ext_vector_type(4)));
typedef float    f4 __attribute__((ext_vector_type(4)));
typedef int      i4v __attribute__((ext_vector_type(4)));

// monotone float<->uint encoding for atomicMax on fp32
__device__ __forceinline__ unsigned fenc(float x) {
  unsigned u = __float_as_uint(x);
  return (u & 0x80000000u) ? ~u : (u | 0x80000000u);
}
__device__ __forceinline__ float fdec(unsigned e) {
  unsigned u = (e & 0x80000000u) ? (e ^ 0x80000000u) : ~e;
  return __uint_as_float(u);
}

// lgkm-only barrier (CK block_sync_lds pattern): publishes LDS writes without
// draining vmem (plain __syncthreads emits s_waitcnt vmcnt(0) -> kills the
// adj prefetch pipeline).
__device__ __forceinline__ void sync_lds() {
  __builtin_amdgcn_s_waitcnt(0xc07f);   // lgkmcnt(0), vmcnt/expcnt ignored
  __builtin_amdgcn_s_barrier();
}

// ---------------- Kernel 1: Wh = h@W (fp32 vector), s1, s2(f16), wfrag -------
// grid 512 x 256 thr. Block = 16 rows of h = half of k-tile (blockIdx>>1).
// wfrag[(kt*16+n)*512 + lane*8 + j] = Wh[kt*32 + (lane>>4)*8 + j][n*16 + (lane&15)]
// R4 fix: s2max via per-block LDS reduction + ONE atomicMax per block
// (was 8192 single-address device atomics -> ~90 us serialization tail).
__global__ __launch_bounds__(256) void k_wh(
    const float* __restrict__ h, const float* __restrict__ W,
    const float* __restrict__ a, _Float16* __restrict__ wfrag,
    float* __restrict__ s1, _Float16* __restrict__ s2h,
    unsigned* __restrict__ s2maxe) {
  __shared__ float hs[16 * 256];        // 16 KB
  __shared__ _Float16 whs[16 * 264];    // 8.25 KB
  __shared__ unsigned bm[4];            // per-wave p2-max (fenc domain)
  const int t = threadIdx.x;
  const int r0 = blockIdx.x * 16;
#pragma unroll
  for (int i = 0; i < 4; ++i) {
    int idx = i * 1024 + t * 4;
    *(f4*)&hs[idx] = *(const f4*)&h[(size_t)r0 * 256 + idx];
  }
  __syncthreads();
  const int lane = t & 63;
  const int wv = t >> 6;        // 0..3
  const int rg = wv * 4;
  const int c4 = lane * 4;
  float acc[4][4];
#pragma unroll
  for (int i = 0; i < 4; ++i)
#pragma unroll
    for (int k = 0; k < 4; ++k) acc[i][k] = 0.f;
  f4 w[8];
#pragma unroll
  for (int i = 0; i < 8; ++i) w[i] = *(const f4*)&W[i * 256 + c4];
  for (int f = 0; f < 256; f += 8) {
    f4 nw[8];
    if (f < 248) {
#pragma unroll
      for (int i = 0; i < 8; ++i) nw[i] = *(const f4*)&W[(f + 8 + i) * 256 + c4];
    }
#pragma unroll
    for (int i = 0; i < 4; ++i) {
      f4 h0 = *(const f4*)&hs[(rg + i) * 256 + f];
      f4 h1 = *(const f4*)&hs[(rg + i) * 256 + f + 4];
#pragma unroll
      for (int k = 0; k < 4; ++k)
        acc[i][k] += h0[0]*w[0][k] + h0[1]*w[1][k] + h0[2]*w[2][k] + h0[3]*w[3][k]
                   + h1[0]*w[4][k] + h1[1]*w[5][k] + h1[2]*w[6][k] + h1[3]*w[7][k];
    }
    if (f < 248) {
#pragma unroll
      for (int i = 0; i < 8; ++i) w[i] = nw[i];
    }
  }
  float a1v[4], a2v[4];
#pragma unroll
  for (int k = 0; k < 4; ++k) { a1v[k] = a[c4 + k]; a2v[k] = a[256 + c4 + k]; }
  unsigned wmax = 0u;   // fenc domain: 0 < fenc(x) for all finite x
#pragma unroll
  for (int i = 0; i < 4; ++i) {
    h4 hh;
    float p1 = 0.f, p2 = 0.f;
#pragma unroll
    for (int k = 0; k < 4; ++k) {
      hh[k] = (_Float16)acc[i][k];
      p1 += acc[i][k] * a1v[k];
      p2 += acc[i][k] * a2v[k];
    }
    *(h4*)&whs[(rg + i) * 264 + c4] = hh;
#pragma unroll
    for (int off = 32; off; off >>= 1) {
      p1 += __shfl_xor(p1, off);
      p2 += __shfl_xor(p2, off);
    }
    if (lane == 0) {
      const int r = r0 + rg + i;
      s1[r] = p1;
      s2h[r] = (_Float16)p2;
      const unsigned e = fenc(p2);
      wmax = (e > wmax) ? e : wmax;
    }
  }
  if (lane == 0) bm[wv] = wmax;
  __syncthreads();
  if (t == 0) {
    unsigned m01 = (bm[0] > bm[1]) ? bm[0] : bm[1];
    unsigned m23 = (bm[2] > bm[3]) ? bm[2] : bm[3];
    atomicMax(s2maxe, (m01 > m23) ? m01 : m23);   // 1 atomic per block (512 total)
  }
  {
    const int kt = blockIdx.x >> 1;
    const int hb = blockIdx.x & 1;
    const int lp = hb * 32 + (t & 31);
    const int kb = ((t & 31) >> 4) * 8;
    const int m16e = t & 15;
#pragma unroll
    for (int p = 0; p < 2; ++p) {
      const int n = (t >> 5) + p * 8;
      h8 v;
#pragma unroll
      for (int j = 0; j < 8; ++j) v[j] = whs[(kb + j) * 264 + n * 16 + m16e];
      *(h8*)&wfrag[(((size_t)kt * 16 + n) << 9) + lp * 8] = v;
    }
  }
}

// ---------------- Kernel 2: fused attention ----------------------------------
// FINAL (R5 structure, best measured: 418.7 us total). Ledger of attempted
// k_gat variants, all within-harness A/B'd against this base:
//   nt adj loads (R1) +13 | 64-row tiling (R2) ~0 | LB(512,8) (R6) spill 5x |
//   32-row x1024 blocks (R7) +10 | scores(p+1)||MFMA(p) SW-pipe (R9) +5 |
//   2m x 4n wave partition (R10) +15.
// k_gat = 73 us vs 48 us HBM floor (268 MB adj mandatory, int32 format fixed);
// residual is DISTRIBUTED (R4 probe: hbm 32%, VALU 35%, Mfma 20%, occ 37%) --
// no single >=10% term remains.
// grid 512 = (rt 0..127) x (kq 0..3); 512 thr; LB(512,4) -> 2 blocks/CU.
// Block: 64 rows x 256 cols x 2048 k. Period = 128 k (16 periods).
__global__ __launch_bounds__(512, 4) void k_gat(
    const int* __restrict__ adj, const _Float16* __restrict__ wfrag,
    const float* __restrict__ s1g, const _Float16* __restrict__ s2h,
    const unsigned* __restrict__ s2maxe,
    float* __restrict__ o0, float* __restrict__ o1,
    float* __restrict__ o2, float* __restrict__ o3,
    float* __restrict__ lbuf) {
  __shared__ _Float16 P[2][64 * PST];   // 34 KB
  __shared__ _Float16 s2l[2048];        // 4 KB
  const int t = threadIdx.x;
  const int lane = t & 63;
  const int w = t >> 6;          // 0..7: score rows {8w+q, 8w+q+4}; cols [32w,32w+32)
  const int q = lane >> 4;       // 0..3
  const int m16 = lane & 15;
  const int rt = (int)blockIdx.x >> 2;
  const int kq = (int)blockIdx.x & 3;
  const int r0 = rt * 64;

  if (t < 256) ((h8*)s2l)[t] = ((const h8*)(s2h + kq * 2048))[t];  // kq-quarter s2

  const int srA = 8 * w + q;                 // lane's two score rows (local)
  const int srB = srA + 4;
  const float s2m = fdec(*s2maxe);
  const float s1A = s1g[r0 + srA];
  const float s1B = s1g[r0 + srB];
  const float uA0 = s1A + s2m, uB0 = s1B + s2m;
  const float miA = fmaxf(uA0, 0.2f * uA0);  // >= leaky(s1+s2[j]) for all j
  const float miB = fmaxf(uB0, 0.2f * uB0);
  const float sAmi = s1A - miA, sBmi = s1B - miB;

  f4 acc[4][2];
#pragma unroll
  for (int m = 0; m < 4; ++m)
#pragma unroll
    for (int n = 0; n < 2; ++n)
#pragma unroll
      for (int e = 0; e < 4; ++e) acc[m][n][e] = 0.f;
  float lsA = 0.f, lsB = 0.f;

  const int* adjA = adj + (size_t)(r0 + srA) * NN + kq * 2048 + m16 * 8;
  const int* adjB = adj + (size_t)(r0 + srB) * NN + kq * 2048 + m16 * 8;
  __syncthreads();   // s2l ready (once; full drain harmless here)

  // preload adj for period 0
  i4v a0 = *(const i4v*)(adjA);
  i4v a1 = *(const i4v*)(adjA + 4);
  i4v b0 = *(const i4v*)(adjB);
  i4v b1 = *(const i4v*)(adjB + 4);

  for (int p = 0; p < 16; ++p) {
    // (1) B-frags for this period: 4 k-subtiles x 2 n-tiles, coalesced L2 loads
    const _Float16* wfb =
        wfrag + ((((size_t)(kq * 64 + p * 4)) * 16 + 2 * w) << 9) + lane * 8;
    h8 bb[8];
#pragma unroll
    for (int ks = 0; ks < 4; ++ks) {
      bb[2 * ks]     = *(const h8*)(wfb + ks * 8192);
      bb[2 * ks + 1] = *(const h8*)(wfb + ks * 8192 + 512);
    }
    // (2) adj prefetch for p+1 (HBM; consumed next period)
    i4v na0 = a0, na1 = a1, nb0 = b0, nb1 = b1;
    if (p < 15) {
      na0 = *(const i4v*)(adjA + (p + 1) * 128);
      na1 = *(const i4v*)(adjA + (p + 1) * 128 + 4);
      nb0 = *(const i4v*)(adjB + (p + 1) * 128);
      nb1 = *(const i4v*)(adjB + (p + 1) * 128 + 4);
    }
    // (3) scores for both rows: p = exp(leaky(s1+s2) - mi)
    const h8 s2c = *(const h8*)&s2l[p * 128 + m16 * 8];
    h8 pA, pB;
#pragma unroll
    for (int j = 0; j < 8; ++j) {
      const float s2v = (float)s2c[j];
      const int mA = (j < 4) ? a0[j] : a1[j - 4];
      const int mB = (j < 4) ? b0[j] : b1[j - 4];
      const float uA = s1A + s2v;
      const float uB = s1B + s2v;
      const float argA = sAmi + s2v - 0.8f * fminf(uA, 0.f);
      const float argB = sBmi + s2v - 0.8f * fminf(uB, 0.f);
      const float pvA = (mA > 0) ? __expf(argA) : 0.f;
      const float pvB = (mB > 0) ? __expf(argB) : 0.f;
      lsA += pvA; pA[j] = (_Float16)pvA;
      lsB += pvB; pB[j] = (_Float16)pvB;
    }
    _Float16* Pb = &P[p & 1][0];
    *(h8*)&Pb[srA * PST + m16 * 8] = pA;
    *(h8*)&Pb[srB * PST + m16 * 8] = pB;
    // (4) publish P without draining vmem
    sync_lds();
    // (5) MFMA: A from LDS (4 m-tiles), B from regs (issued at (1))
#pragma unroll
    for (int ks = 0; ks < 4; ++ks) {
      const h8 A0 = *(const h8*)&Pb[(     m16) * PST + ks * 32 + q * 8];
      const h8 A1 = *(const h8*)&Pb[(16 + m16) * PST + ks * 32 + q * 8];
      const h8 A2 = *(const h8*)&Pb[(32 + m16) * PST + ks * 32 + q * 8];
      const h8 A3 = *(const h8*)&Pb[(48 + m16) * PST + ks * 32 + q * 8];
      acc[0][0] = __builtin_amdgcn_mfma_f32_16x16x32_f16(A0, bb[2*ks],   acc[0][0], 0, 0, 0);
      acc[0][1] = __builtin_amdgcn_mfma_f32_16x16x32_f16(A0, bb[2*ks+1], acc[0][1], 0, 0, 0);
      acc[1][0] = __builtin_amdgcn_mfma_f32_16x16x32_f16(A1, bb[2*ks],   acc[1][0], 0, 0, 0);
      acc[1][1] = __builtin_amdgcn_mfma_f32_16x16x32_f16(A1, bb[2*ks+1], acc[1][1], 0, 0, 0);
      acc[2][0] = __builtin_amdgcn_mfma_f32_16x16x32_f16(A2, bb[2*ks],   acc[2][0], 0, 0, 0);
      acc[2][1] = __builtin_amdgcn_mfma_f32_16x16x32_f16(A2, bb[2*ks+1], acc[2][1], 0, 0, 0);
      acc[3][0] = __builtin_amdgcn_mfma_f32_16x16x32_f16(A3, bb[2*ks],   acc[3][0], 0, 0, 0);
      acc[3][1] = __builtin_amdgcn_mfma_f32_16x16x32_f16(A3, bb[2*ks+1], acc[3][1], 0, 0, 0);
    }
    a0 = na0; a1 = na1; b0 = nb0; b1 = nb1;
  }

  // partial softmax denominators: reduce over the 16 m16 lanes
  lsA += __shfl_xor(lsA, 1);
  lsA += __shfl_xor(lsA, 2);
  lsA += __shfl_xor(lsA, 4);
  lsA += __shfl_xor(lsA, 8);
  lsB += __shfl_xor(lsB, 1);
  lsB += __shfl_xor(lsB, 2);
  lsB += __shfl_xor(lsB, 4);
  lsB += __shfl_xor(lsB, 8);
  if (m16 == 0) {
    lbuf[kq * NN + r0 + srA] = lsA;
    lbuf[kq * NN + r0 + srB] = lsB;
  }

  // partial O: plain stores (each element written once per kq)
  float* ob = (kq == 0) ? o0 : (kq == 1) ? o1 : (kq == 2) ? o2 : o3;
#pragma unroll
  for (int m = 0; m < 4; ++m)
#pragma unroll
    for (int n = 0; n < 2; ++n)
#pragma unroll
      for (int v = 0; v < 4; ++v)
        ob[(size_t)(r0 + m * 16 + q * 4 + v) * FF + w * 32 + n * 16 + m16] =
            acc[m][n][v];
}

// ---------------- Kernel 3: combine quarters, normalize, elu -----------------
__global__ __launch_bounds__(256) void k_fin(
    float* __restrict__ out, const float* __restrict__ o1,
    const float* __restrict__ o2, const float* __restrict__ o3,
    const float* __restrict__ lbuf) {
  const int t = threadIdx.x;
  const int row = blockIdx.x * 16 + (t >> 4);
  const int c0 = (t & 15) * 16;
  const float linv = 1.0f / (lbuf[row] + lbuf[NN + row] +
                             lbuf[2 * NN + row] + lbuf[3 * NN + row]);
#pragma unroll
  for (int i = 0; i < 4; ++i) {
    f4 v0 = *(const f4*)&out[(size_t)row * FF + c0 + i * 4];
    f4 v1 = *(const f4*)&o1[(size_t)row * FF + c0 + i * 4];
    f4 v2 = *(const f4*)&o2[(size_t)row * FF + c0 + i * 4];
    f4 v3 = *(const f4*)&o3[(size_t)row * FF + c0 + i * 4];
    f4 o;
#pragma unroll
    for (int e = 0; e < 4; ++e) {
      float x = (v0[e] + v1[e] + v2[e] + v3[e]) * linv;
      o[e] = (x > 0.f) ? x : (__expf(x) - 1.f);
    }
    *(f4*)&out[(size_t)row * FF + c0 + i * 4] = o;
  }
}

extern "C" void kernel_launch(void* const* d_in, const int* in_sizes, int n_in,
                              void* d_out, int out_size, void* d_ws, size_t ws_size,
                              hipStream_t stream) {
  const float* h   = (const float*)d_in[0];
  const int*   adj = (const int*)d_in[1];
  const float* W   = (const float*)d_in[2];
  const float* a   = (const float*)d_in[3];
  float* out = (float*)d_out;

  char* ws = (char*)d_ws;
  _Float16* wfrag = (_Float16*)ws;                                 // 4 MB
  float*    o1    = (float*)(ws + (4u << 20));                     // 8 MB (kq=1)
  float*    o2    = (float*)(ws + (12u << 20));                    // 8 MB (kq=2)
  float*    o3    = (float*)(ws + (20u << 20));                    // 8 MB (kq=3)
  float*    lbuf  = (float*)(ws + (28u << 20));                    // 128 KB (4 x 8192)
  unsigned* s2me  = (unsigned*)(ws + (28u << 20) + 131072);        // 4 B (+60 pad)
  float*    s1    = (float*)(ws + (28u << 20) + 131072 + 64);      // 32 KB
  _Float16* s2h   = (_Float16*)(ws + (28u << 20) + 131072 + 64 + 32768); // 16 KB

  hipMemsetAsync(s2me, 0, 4, stream);   // fenc-domain -inf
  k_wh<<<512, 256, 0, stream>>>(h, W, a, wfrag, s1, s2h, s2me);
  k_gat<<<512, 512, 0, stream>>>(adj, wfrag, s1, s2h, s2me, out, o1, o2, o3, lbuf);
  k_fin<<<512, 256, 0, stream>>>(out, o1, o2, o3, lbuf);
}